// Round 20
// baseline (37.025 us; speedup 1.0000x reference)
//
#include <hip/hip_runtime.h>
#include <math.h>

// ---------------------------------------------------------------------------
// CAM_Net fused pipeline, MI355X (gfx950) — round 20
//
// vs round 19 (best known, 29.69us): ONE isolated change — the conv halo
// is no longer fetched with __shfl_up/__shfl_down (48 ds_permute ops per
// thread INSIDE the compute phase, each an lgkmcnt stall), but with two
// prefetchable scalar loads per row (L = xrow[4cg-1], R = xrow[4cg+4],
// clamped; edge lanes were already mask-multiplied). They ride in the
// existing 2-stage channel preload, so the compute phase is pure FMA +
// LDS weight reads. +16 VGPR (~116, below the 128 spill cliff).
//
// Everything else identical to r19: two launches, side blocks last,
// per-block M=W3@C1 fold, KT/VT stride 272, 2-thr/pixel one-pass softmax,
// rect-sum stats, G-folded tail. No atomics; deterministic.
// ---------------------------------------------------------------------------

#define OFF_STATA ((size_t)0)       // 3072
#define OFF_SX    ((size_t)3072)    // 54 (pad to 3136)
#define OFF_G     ((size_t)3136)    // 20*288 = 5760
#define OFF_GB    ((size_t)8896)    // 20*54 = 1080
#define OFF_FCB2  ((size_t)9976)    // 20

// smem float offsets (k_fused main blocks)
#define SM_KT   0        // 8*272 = 2176
#define SM_VT   2176     // 8*272 = 2176
#define SM_QS   4352     // 2*256
#define SM_ML   4864     // 168
#define SM_BIAS 5032     // 8
#define SM_RW   5040     // 16 (rhs 0-6, rws 8-14)
#define SM_RED  5056     // 64
#define SM_TOT  5120     // 20480 bytes

// K1: fused everything-before-the-tail.
//  bid < 1024          : main (c = bid>>5, oy = bid&31)
//  bid in [1024,1078)  : Sx strided sums (54)
//  bid in [1078,1185)  : G/Gb fold (107)
//  bid in [1185,1205)  : fcb' (20)
__global__ __launch_bounds__(256) void k_fused(
    const float* __restrict__ x,
    const float* __restrict__ c1w, const float* __restrict__ c1b,
    const float* __restrict__ kw, const float* __restrict__ kb,
    const float* __restrict__ qw, const float* __restrict__ qb,
    const float* __restrict__ vw, const float* __restrict__ vb,
    const float* __restrict__ relh, const float* __restrict__ relw,
    const float* __restrict__ bw, const float* __restrict__ bb,
    const float* __restrict__ ew, const float* __restrict__ eb,
    const float* __restrict__ fcw, const float* __restrict__ fcb,
    float* __restrict__ statA, float* __restrict__ Sx,
    float* __restrict__ G, float* __restrict__ Gb,
    float* __restrict__ FCB2) {
  __shared__ float smem[SM_TOT];
  int tid = threadIdx.x;
  int bid = blockIdx.x;

  // ---- side blocks --------------------------------------------------------
  if (bid >= 1024) {
    float* red2 = smem;                    // 256 scratch
    if (bid < 1078) {                      // Sx
      int e = bid - 1024;
      int ci = e / 9, rem = e - ci * 9, ky = rem / 3, kx = rem - ky * 3;
      const float* xc = x + (size_t)ci * 65536;
      float acc = 0.f;
      for (int p = tid; p < 1024; p += 256) {
        int oy = p >> 5, ox = p & 31;
        int ry = 8 * oy - 1 + ky, cx = 8 * ox - 1 + kx;
        if (ry >= 0 && ry <= 255 && cx >= 0 && cx <= 255)
          acc += xc[ry * 256 + cx];
      }
      #pragma unroll
      for (int off = 32; off >= 1; off >>= 1) acc += __shfl_down(acc, off);
      if ((tid & 63) == 0) red2[tid >> 6] = acc;
      __syncthreads();
      if (tid == 0) Sx[e] = red2[0] + red2[1] + red2[2] + red2[3];
      return;
    }
    if (bid < 1185) {                      // G/Gb fold, 64 outputs/block
      int gi0 = (bid - 1078) * 64;
      int l = tid & 63, w = tid >> 6;
      int g = gi0 + l;                     // 0..6847 (6840 valid)
      int o = g / 342;
      int i = g - o * 342;
      bool valid = (g < 6840);
      int oc = valid ? o : 0;
      float acc = 0.f;
      const float* fr = fcw + oc * 512;
      #pragma unroll 8
      for (int mm = 0; mm < 128; ++mm) {
        int m = w * 128 + mm;
        float val = (i < 288) ? ew[m * 288 + i] : bw[m * 54 + (i - 288)];
        acc = fmaf(fr[m], val, acc);
      }
      red2[tid] = acc;
      __syncthreads();
      if (w == 0 && valid) {
        float s = red2[l] + red2[64 + l] + red2[128 + l] + red2[192 + l];
        if (i < 288) G[o * 288 + i] = s;
        else         Gb[o * 54 + (i - 288)] = s;
      }
      return;
    }
    {                                      // fcb'
      int o = bid - 1185;
      float acc = fmaf(fcw[o * 512 + tid], bb[tid] + eb[tid],
                       fcw[o * 512 + 256 + tid] * (bb[256 + tid] + eb[256 + tid]));
      #pragma unroll
      for (int off = 32; off >= 1; off >>= 1) acc += __shfl_down(acc, off);
      if ((tid & 63) == 0) red2[tid >> 6] = acc;
      __syncthreads();
      if (tid == 0) FCB2[o] = fcb[o] + red2[0] + red2[1] + red2[2] + red2[3];
      return;
    }
  }

  // ---- main blocks: (c, oy) ----------------------------------------------
  int c  = bid >> 5;
  int oy = bid & 31;

  float* KT  = smem + SM_KT;               // 8 x 272
  float* VT  = smem + SM_VT;               // 8 x 272
  float* QS  = smem + SM_QS;
  float* Ml  = smem + SM_ML;
  float* bsl = smem + SM_BIAS;
  float* rhs = smem + SM_RW;               // [0..6]
  float* rws = smem + SM_RW + 8;           // [0..6]
  float* red = smem + SM_RED;

  // conv geometry (needed for the preload)
  int cg = tid & 63, rg = tid >> 6;
  int roq = (rg == 1) ? 1 : ((rg == 2) ? 0 : -1);   // q rows: x1 rel 3, 4
  int xr0 = 8 * oy + 2 * rg - 1;
  int colL = max(4 * cg - 1, 0);
  int colR = min(4 * cg + 4, 255);

  // issue ci=0's row + halo loads NOW — independent of the fold below; the
  // fold's serial FMA chain hides their L2 latency.
  float4 Bv4[4];
  float  Lh[4], Rh[4];
  #pragma unroll
  for (int s4 = 0; s4 < 4; ++s4) {
    int xr = xr0 + s4;
    int xrc = min(max(xr, 0), 255);
    const float* xrow = &x[xrc * 256];
    Bv4[s4] = *(const float4*)&xrow[4 * cg];
    Lh[s4]  = xrow[colL];
    Rh[s4]  = xrow[colR];
  }

  // Phase 0: per-block weight fold M = W3@C1 + biases + rel reductions
  if (tid < 168) {
    int ci = tid / 28, s = tid - ci * 28;
    if (s < 27) {
      int kind = s / 9, t9 = s - kind * 9;
      const float* w3 = (kind == 0 ? kw : (kind == 1 ? vw : qw)) + c * 32;
      float a = 0.f;
      #pragma unroll
      for (int m = 0; m < 32; ++m)
        a = fmaf(w3[m], c1w[(m * 6 + ci) * 9 + t9], a);
      Ml[ci * 28 + s] = a;
    }
  } else if (tid < 176) {
    int s = tid - 168;
    if (s < 3) {
      const float* w3 = (s == 0 ? kw : (s == 1 ? vw : qw)) + c * 32;
      float a = (s == 0 ? kb : (s == 1 ? vb : qb))[c];
      #pragma unroll
      for (int m = 0; m < 32; ++m) a = fmaf(w3[m], c1b[m], a);
      bsl[s] = a;
    } else if (s == 3) bsl[3] = kb[c];
    else if (s == 4) bsl[4] = vb[c];
  } else if (tid < 184) {
    int i = tid - 176;
    if (i < 7) {
      float s = 0.f;
      for (int cc = 0; cc < 16; ++cc) s += relh[cc * 7 + i];
      rhs[i] = s;
    }
  } else if (tid < 192) {
    int j = tid - 184;
    if (j < 7) {
      float s = 0.f;
      for (int cc = 0; cc < 16; ++cc) s += relw[cc * 7 + j];
      rws[j] = s;
    }
  }
  __syncthreads();

  // conv accumulators
  float kacc[2][4], vacc[2][4], qacc[4];
  {
    float mk = bsl[0], mv = bsl[1], mq = bsl[2];
    #pragma unroll
    for (int ro = 0; ro < 2; ++ro)
      #pragma unroll
      for (int cc = 0; cc < 4; ++cc) { kacc[ro][cc] = mk; vacc[ro][cc] = mv; }
    #pragma unroll
    for (int cc = 0; cc < 4; ++cc) qacc[cc] = mq;
  }
  float mA = (cg > 0) ? 1.0f : 0.0f;
  float mC = (cg < 63) ? 1.0f : 0.0f;

  // 2-stage pipelined channel loop: compute ci from resident regs, prefetch
  // ci+1 (row quad + halo scalars). Compute phase has NO cross-lane ops.
  #pragma unroll 1
  for (int ci = 0; ci < 6; ++ci) {
    float4 Bn4[4];
    float  Ln[4], Rn[4];
    if (ci < 5) {
      const float* xnx = x + (size_t)(ci + 1) * 65536;
      #pragma unroll
      for (int s4 = 0; s4 < 4; ++s4) {
        int xr = xr0 + s4;
        int xrc = min(max(xr, 0), 255);
        const float* xrow = &xnx[xrc * 256];
        Bn4[s4] = *(const float4*)&xrow[4 * cg];
        Ln[s4]  = xrow[colL];
        Rn[s4]  = xrow[colR];
      }
    }
    float wch[28];
    {
      const float4* Mc = (const float4*)&Ml[ci * 28];
      *(float4*)&wch[0]  = Mc[0]; *(float4*)&wch[4]  = Mc[1];
      *(float4*)&wch[8]  = Mc[2]; *(float4*)&wch[12] = Mc[3];
      *(float4*)&wch[16] = Mc[4]; *(float4*)&wch[20] = Mc[5];
      *(float4*)&wch[24] = Mc[6];
    }
    #pragma unroll
    for (int s4 = 0; s4 < 4; ++s4) {
      int xr = xr0 + s4;
      if (xr < 0 || xr > 255) continue;    // wave-uniform (rg per wave)
      float4 Bv = Bv4[s4];
      float win[6];
      win[0] = Lh[s4] * mA;
      win[1] = Bv.x;
      win[2] = Bv.y;
      win[3] = Bv.z;
      win[4] = Bv.w;
      win[5] = Rh[s4] * mC;
      if (s4 < 3) {                        // ro=0, weight row s4
        const float* wk = &wch[3 * s4];
        const float* wv = &wch[9 + 3 * s4];
        #pragma unroll
        for (int cc = 0; cc < 4; ++cc) {
          float a = kacc[0][cc], b2 = vacc[0][cc];
          #pragma unroll
          for (int dxw = 0; dxw < 3; ++dxw) {
            float xv = win[cc + dxw];
            a  = fmaf(wk[dxw], xv, a);
            b2 = fmaf(wv[dxw], xv, b2);
          }
          kacc[0][cc] = a; vacc[0][cc] = b2;
        }
        if (roq == 0) {
          const float* wq = &wch[18 + 3 * s4];
          #pragma unroll
          for (int cc = 0; cc < 4; ++cc) {
            float qa = qacc[cc];
            #pragma unroll
            for (int dxw = 0; dxw < 3; ++dxw)
              qa = fmaf(wq[dxw], win[cc + dxw], qa);
            qacc[cc] = qa;
          }
        }
      }
      if (s4 >= 1) {                       // ro=1, weight row s4-1
        const float* wk = &wch[3 * (s4 - 1)];
        const float* wv = &wch[9 + 3 * (s4 - 1)];
        #pragma unroll
        for (int cc = 0; cc < 4; ++cc) {
          float a = kacc[1][cc], b2 = vacc[1][cc];
          #pragma unroll
          for (int dxw = 0; dxw < 3; ++dxw) {
            float xv = win[cc + dxw];
            a  = fmaf(wk[dxw], xv, a);
            b2 = fmaf(wv[dxw], xv, b2);
          }
          kacc[1][cc] = a; vacc[1][cc] = b2;
        }
        if (roq == 1) {
          const float* wq = &wch[18 + 3 * (s4 - 1)];
          #pragma unroll
          for (int cc = 0; cc < 4; ++cc) {
            float qa = qacc[cc];
            #pragma unroll
            for (int dxw = 0; dxw < 3; ++dxw)
              qa = fmaf(wq[dxw], win[cc + dxw], qa);
            qacc[cc] = qa;
          }
        }
      }
    }
    if (ci < 5) {
      #pragma unroll
      for (int s4 = 0; s4 < 4; ++s4) {
        Bv4[s4] = Bn4[s4]; Lh[s4] = Ln[s4]; Rh[s4] = Rn[s4];
      }
    }
  }

  // write K/V tiles (x1 col xc at slot xc+4, stride 272) + q + bias pad cols
  #pragma unroll
  for (int ro = 0; ro < 2; ++ro) {
    int r = 2 * rg + ro;
    *(float4*)&KT[r * 272 + 4 * cg + 4] =
        make_float4(kacc[ro][0], kacc[ro][1], kacc[ro][2], kacc[ro][3]);
    *(float4*)&VT[r * 272 + 4 * cg + 4] =
        make_float4(vacc[ro][0], vacc[ro][1], vacc[ro][2], vacc[ro][3]);
  }
  if (roq >= 0)
    *(float4*)&QS[(rg == 2 ? 256 : 0) + 4 * cg] =
        make_float4(qacc[0], qacc[1], qacc[2], qacc[3]);
  if (tid < 96) {                          // pad cols pc 0,1,2,259,260,261
    int t2 = tid;
    int kv = t2 >= 48; if (kv) t2 -= 48;
    int lr = t2 & 7, pi = t2 >> 3;
    int slot = (pi < 3) ? (pi + 1) : (pi + 257);
    (kv ? VT : KT)[lr * 272 + slot] = bsl[3 + kv];
  }
  __syncthreads();

  // ---- attention: 2 thr/pixel, one-pass softmax --------------------------
  {
    int half = tid & 1;
    int pix  = tid >> 1;
    int dx   = pix & 1;
    int ox   = (pix >> 1) & 31;
    int dy   = (pix >> 6) & 1;
    int wb   = 8 * ox + 4 * dx;
    int dv   = dx ? 0 : 3;
    int i0   = half * 3;

    float4 qv4 = *(const float4*)&QS[dy * 256 + wb];
    float qv0 = qv4.x, qv1 = qv4.y, qv2 = qv4.z, qv3 = qv4.w;
    float qsum = qv0 + qv1 + qv2 + qv3;

    float sum = 0.f, o = 0.f;
    #pragma unroll
    for (int ii = 0; ii < 4; ++ii) {
      int i = i0 + ii;
      float act = ((half == 0) || (ii > 0)) ? 1.0f : 0.0f;
      const float* kr = &KT[(dy + i) * 272 + wb];
      const float* vr = &VT[(dy + i) * 272 + wb];
      float B[12], BV[12];
      *(float4*)&B[0]  = *(const float4*)&kr[0];
      *(float4*)&B[4]  = *(const float4*)&kr[4];
      *(float4*)&B[8]  = *(const float4*)&kr[8];
      *(float4*)&BV[0] = *(const float4*)&vr[0];
      *(float4*)&BV[4] = *(const float4*)&vr[4];
      *(float4*)&BV[8] = *(const float4*)&vr[8];
      float rh = rhs[i];
      #pragma unroll
      for (int j = 0; j < 7; ++j) {
        float d0 = fmaf(qv0, B[j + 1],
                   fmaf(qv1, B[j + 2],
                   fmaf(qv2, B[j + 3], qv3 * B[j + 4])));
        float s = fmaf(qsum, rh + rws[j], d0);
        float e = act * __expf(s);
        sum += e;
        o = fmaf(e, BV[dv + j + 1], o);
      }
    }
    sum += __shfl_xor(sum, 1);
    o   += __shfl_xor(o, 1);

    float quarter = 0.25f * o / sum;
    float psum = quarter + __shfl_xor(quarter, 2);
    if ((tid & 3) == 0) red[dy * 32 + ox] = psum;
  }
  __syncthreads();

  if (tid < 32) {
    float scv = red[tid] + red[32 + tid];  // sc[c][oy][tid]
    float e0  = __shfl(scv, 0, 32);
    float e31 = __shfl(scv, 31, 32);
    float rs = scv;
    #pragma unroll
    for (int off = 16; off >= 1; off >>= 1) rs += __shfl_down(rs, off, 32);
    if (tid == 0) {
      float* pa = statA + (c * 32 + oy) * 3;
      pa[0] = rs; pa[1] = e0; pa[2] = e31;
    }
  }
}

// K2: out[o] = fcb'[o] + (G[o,:].S + Gb[o,:].Sx)/1024. 20 blocks x 64 lanes.
__global__ __launch_bounds__(64) void k_out(
    const float* __restrict__ statA, const float* __restrict__ Sx,
    const float* __restrict__ G, const float* __restrict__ Gb,
    const float* __restrict__ FCB2, float* __restrict__ out) {
  __shared__ float Sl[288];
  __shared__ float SxL[54];
  int o = blockIdx.x, lane = threadIdx.x;
  if (lane < 32) {
    int ch = lane;
    const float* pa = statA + ch * 96;
    float T = 0.f, C0 = 0.f, C31 = 0.f;
    #pragma unroll
    for (int i = 0; i < 32; ++i) {
      T += pa[3 * i]; C0 += pa[3 * i + 1]; C31 += pa[3 * i + 2];
    }
    float r0 = pa[0],  e00 = pa[1],    e0_31 = pa[2];
    float r31 = pa[93], e31_0 = pa[94], e31_31 = pa[95];
    #pragma unroll
    for (int ky = 0; ky < 3; ++ky) {
      float exR = (ky == 0) ? r31 : (ky == 2 ? r0 : 0.f);
      #pragma unroll
      for (int kx = 0; kx < 3; ++kx) {
        float exC = (kx == 0) ? C31 : (kx == 2 ? C0 : 0.f);
        float corner = 0.f;
        if (ky != 1 && kx != 1) {
          if (ky == 0) corner = (kx == 0) ? e31_31 : e31_0;
          else         corner = (kx == 0) ? e0_31  : e00;
        }
        Sl[ch * 9 + ky * 3 + kx] = T - exR - exC + corner;
      }
    }
  } else {
    for (int idx = lane - 32; idx < 54; idx += 32) SxL[idx] = Sx[idx];
  }
  __syncthreads();

  float acc = 0.f;
  #pragma unroll
  for (int i0 = 0; i0 < 288; i0 += 64) {
    int i = i0 + lane;
    if (i < 288) acc = fmaf(G[o * 288 + i], Sl[i], acc);
  }
  if (lane < 54) acc = fmaf(Gb[o * 54 + lane], SxL[lane], acc);
  #pragma unroll
  for (int off = 32; off >= 1; off >>= 1) acc += __shfl_down(acc, off);
  if (lane == 0) out[o] = FCB2[o] + acc * (1.0f / 1024.0f);
}

extern "C" void kernel_launch(void* const* d_in, const int* in_sizes, int n_in,
                              void* d_out, int out_size, void* d_ws, size_t ws_size,
                              hipStream_t stream) {
  const float* x    = (const float*)d_in[0];
  // d_in[1] = diff_input (int, always 1) -> attention branch always taken
  const float* bw   = (const float*)d_in[2];
  const float* bb   = (const float*)d_in[3];
  const float* c1w  = (const float*)d_in[4];
  const float* c1b  = (const float*)d_in[5];
  const float* kw   = (const float*)d_in[6];
  const float* kb   = (const float*)d_in[7];
  const float* qw   = (const float*)d_in[8];
  const float* qb   = (const float*)d_in[9];
  const float* vw   = (const float*)d_in[10];
  const float* vb   = (const float*)d_in[11];
  const float* relh = (const float*)d_in[12];
  const float* relw = (const float*)d_in[13];
  const float* ew   = (const float*)d_in[14];
  const float* eb   = (const float*)d_in[15];
  const float* fcw  = (const float*)d_in[16];
  const float* fcb  = (const float*)d_in[17];

  float* ws    = (float*)d_ws;
  float* statA = ws + OFF_STATA;
  float* Sxb   = ws + OFF_SX;
  float* Gm    = ws + OFF_G;
  float* Gbm   = ws + OFF_GB;
  float* FCB2  = ws + OFF_FCB2;
  float* out   = (float*)d_out;

  k_fused<<<1205, 256, 0, stream>>>(x, c1w, c1b, kw, kb, qw, qb, vw, vb,
                                    relh, relw, bw, bb, ew, eb, fcw, fcb,
                                    statA, Sxb, Gm, Gbm, FCB2);
  k_out  <<<20,   64,  0, stream>>>(statA, Sxb, Gm, Gbm, FCB2, out);
}

// Round 21
// 29.648 us; speedup vs baseline: 1.2488x; 1.2488x over previous
//
#include <hip/hip_runtime.h>
#include <math.h>

// ---------------------------------------------------------------------------
// CAM_Net fused pipeline, MI355X (gfx950) — round 21 (= r16/r19, best known)
//
// r20's shfl->scalar-halo regressed (37.0us: 3x VMEM instruction count beat
// the lgkmcnt saving). This is the measured-best configuration, reproduced
// at 29.69-29.79us in rounds 14/16/19: two launches, side blocks last,
// shfl-halo conv, 2-stage channel preload.
//
// Perturbation ledger (all from this base): wider blocks +1.6us (r15);
// side-first dispatch +1.9us (r17); single-launch fusion +75us regalloc
// collapse (r18); shfl->loads +7.3us (r20); ILP preload ±0 (r16).
// Conclusion: robust local optimum — issue/latency-structure floor
// (VALUBusy ~25%, HBM ~0.5%), not a hardware roofline.
// ---------------------------------------------------------------------------

#define OFF_STATA ((size_t)0)       // 3072
#define OFF_SX    ((size_t)3072)    // 54 (pad to 3136)
#define OFF_G     ((size_t)3136)    // 20*288 = 5760
#define OFF_GB    ((size_t)8896)    // 20*54 = 1080
#define OFF_FCB2  ((size_t)9976)    // 20

// smem float offsets (k_fused main blocks)
#define SM_KT   0        // 8*272 = 2176
#define SM_VT   2176     // 8*272 = 2176
#define SM_QS   4352     // 2*256
#define SM_ML   4864     // 168
#define SM_BIAS 5032     // 8
#define SM_RW   5040     // 16 (rhs 0-6, rws 8-14)
#define SM_RED  5056     // 64
#define SM_TOT  5120     // 20480 bytes

// K1: fused everything-before-the-tail.
//  bid < 1024          : main (c = bid>>5, oy = bid&31)
//  bid in [1024,1078)  : Sx strided sums (54)
//  bid in [1078,1185)  : G/Gb fold (107)
//  bid in [1185,1205)  : fcb' (20)
__global__ __launch_bounds__(256) void k_fused(
    const float* __restrict__ x,
    const float* __restrict__ c1w, const float* __restrict__ c1b,
    const float* __restrict__ kw, const float* __restrict__ kb,
    const float* __restrict__ qw, const float* __restrict__ qb,
    const float* __restrict__ vw, const float* __restrict__ vb,
    const float* __restrict__ relh, const float* __restrict__ relw,
    const float* __restrict__ bw, const float* __restrict__ bb,
    const float* __restrict__ ew, const float* __restrict__ eb,
    const float* __restrict__ fcw, const float* __restrict__ fcb,
    float* __restrict__ statA, float* __restrict__ Sx,
    float* __restrict__ G, float* __restrict__ Gb,
    float* __restrict__ FCB2) {
  __shared__ float smem[SM_TOT];
  int tid = threadIdx.x;
  int bid = blockIdx.x;

  // ---- side blocks --------------------------------------------------------
  if (bid >= 1024) {
    float* red2 = smem;                    // 256 scratch
    if (bid < 1078) {                      // Sx
      int e = bid - 1024;
      int ci = e / 9, rem = e - ci * 9, ky = rem / 3, kx = rem - ky * 3;
      const float* xc = x + (size_t)ci * 65536;
      float acc = 0.f;
      for (int p = tid; p < 1024; p += 256) {
        int oy = p >> 5, ox = p & 31;
        int ry = 8 * oy - 1 + ky, cx = 8 * ox - 1 + kx;
        if (ry >= 0 && ry <= 255 && cx >= 0 && cx <= 255)
          acc += xc[ry * 256 + cx];
      }
      #pragma unroll
      for (int off = 32; off >= 1; off >>= 1) acc += __shfl_down(acc, off);
      if ((tid & 63) == 0) red2[tid >> 6] = acc;
      __syncthreads();
      if (tid == 0) Sx[e] = red2[0] + red2[1] + red2[2] + red2[3];
      return;
    }
    if (bid < 1185) {                      // G/Gb fold, 64 outputs/block
      int gi0 = (bid - 1078) * 64;
      int l = tid & 63, w = tid >> 6;
      int g = gi0 + l;                     // 0..6847 (6840 valid)
      int o = g / 342;
      int i = g - o * 342;
      bool valid = (g < 6840);
      int oc = valid ? o : 0;
      float acc = 0.f;
      const float* fr = fcw + oc * 512;
      #pragma unroll 8
      for (int mm = 0; mm < 128; ++mm) {
        int m = w * 128 + mm;
        float val = (i < 288) ? ew[m * 288 + i] : bw[m * 54 + (i - 288)];
        acc = fmaf(fr[m], val, acc);
      }
      red2[tid] = acc;
      __syncthreads();
      if (w == 0 && valid) {
        float s = red2[l] + red2[64 + l] + red2[128 + l] + red2[192 + l];
        if (i < 288) G[o * 288 + i] = s;
        else         Gb[o * 54 + (i - 288)] = s;
      }
      return;
    }
    {                                      // fcb'
      int o = bid - 1185;
      float acc = fmaf(fcw[o * 512 + tid], bb[tid] + eb[tid],
                       fcw[o * 512 + 256 + tid] * (bb[256 + tid] + eb[256 + tid]));
      #pragma unroll
      for (int off = 32; off >= 1; off >>= 1) acc += __shfl_down(acc, off);
      if ((tid & 63) == 0) red2[tid >> 6] = acc;
      __syncthreads();
      if (tid == 0) FCB2[o] = fcb[o] + red2[0] + red2[1] + red2[2] + red2[3];
      return;
    }
  }

  // ---- main blocks: (c, oy) ----------------------------------------------
  int c  = bid >> 5;
  int oy = bid & 31;

  float* KT  = smem + SM_KT;               // 8 x 272
  float* VT  = smem + SM_VT;               // 8 x 272
  float* QS  = smem + SM_QS;
  float* Ml  = smem + SM_ML;
  float* bsl = smem + SM_BIAS;
  float* rhs = smem + SM_RW;               // [0..6]
  float* rws = smem + SM_RW + 8;           // [0..6]
  float* red = smem + SM_RED;

  // conv geometry (needed for the preload)
  int cg = tid & 63, rg = tid >> 6;
  int roq = (rg == 1) ? 1 : ((rg == 2) ? 0 : -1);   // q rows: x1 rel 3, 4
  int xr0 = 8 * oy + 2 * rg - 1;

  // issue ci=0's row loads NOW — independent of the fold below; the fold's
  // serial FMA chain hides their L2 latency.
  float4 Bv4[4];
  #pragma unroll
  for (int s4 = 0; s4 < 4; ++s4) {
    int xr = xr0 + s4;
    int xrc = min(max(xr, 0), 255);
    Bv4[s4] = *(const float4*)&x[xrc * 256 + 4 * cg];
  }

  // Phase 0: per-block weight fold M = W3@C1 + biases + rel reductions
  if (tid < 168) {
    int ci = tid / 28, s = tid - ci * 28;
    if (s < 27) {
      int kind = s / 9, t9 = s - kind * 9;
      const float* w3 = (kind == 0 ? kw : (kind == 1 ? vw : qw)) + c * 32;
      float a = 0.f;
      #pragma unroll
      for (int m = 0; m < 32; ++m)
        a = fmaf(w3[m], c1w[(m * 6 + ci) * 9 + t9], a);
      Ml[ci * 28 + s] = a;
    }
  } else if (tid < 176) {
    int s = tid - 168;
    if (s < 3) {
      const float* w3 = (s == 0 ? kw : (s == 1 ? vw : qw)) + c * 32;
      float a = (s == 0 ? kb : (s == 1 ? vb : qb))[c];
      #pragma unroll
      for (int m = 0; m < 32; ++m) a = fmaf(w3[m], c1b[m], a);
      bsl[s] = a;
    } else if (s == 3) bsl[3] = kb[c];
    else if (s == 4) bsl[4] = vb[c];
  } else if (tid < 184) {
    int i = tid - 176;
    if (i < 7) {
      float s = 0.f;
      for (int cc = 0; cc < 16; ++cc) s += relh[cc * 7 + i];
      rhs[i] = s;
    }
  } else if (tid < 192) {
    int j = tid - 184;
    if (j < 7) {
      float s = 0.f;
      for (int cc = 0; cc < 16; ++cc) s += relw[cc * 7 + j];
      rws[j] = s;
    }
  }
  __syncthreads();

  // conv accumulators
  float kacc[2][4], vacc[2][4], qacc[4];
  {
    float mk = bsl[0], mv = bsl[1], mq = bsl[2];
    #pragma unroll
    for (int ro = 0; ro < 2; ++ro)
      #pragma unroll
      for (int cc = 0; cc < 4; ++cc) { kacc[ro][cc] = mk; vacc[ro][cc] = mv; }
    #pragma unroll
    for (int cc = 0; cc < 4; ++cc) qacc[cc] = mq;
  }
  float mA = (cg > 0) ? 1.0f : 0.0f;
  float mC = (cg < 63) ? 1.0f : 0.0f;

  // 2-stage pipelined channel loop: compute ci from Bv4, prefetch ci+1 to Bn4.
  #pragma unroll 1
  for (int ci = 0; ci < 6; ++ci) {
    float4 Bn4[4];
    if (ci < 5) {
      const float* xnx = x + (size_t)(ci + 1) * 65536;
      #pragma unroll
      for (int s4 = 0; s4 < 4; ++s4) {
        int xr = xr0 + s4;
        int xrc = min(max(xr, 0), 255);
        Bn4[s4] = *(const float4*)&xnx[xrc * 256 + 4 * cg];
      }
    }
    float wch[28];
    {
      const float4* Mc = (const float4*)&Ml[ci * 28];
      *(float4*)&wch[0]  = Mc[0]; *(float4*)&wch[4]  = Mc[1];
      *(float4*)&wch[8]  = Mc[2]; *(float4*)&wch[12] = Mc[3];
      *(float4*)&wch[16] = Mc[4]; *(float4*)&wch[20] = Mc[5];
      *(float4*)&wch[24] = Mc[6];
    }
    #pragma unroll
    for (int s4 = 0; s4 < 4; ++s4) {
      int xr = xr0 + s4;
      if (xr < 0 || xr > 255) continue;    // wave-uniform (rg per wave)
      float4 Bv = Bv4[s4];
      float left  = __shfl_up(Bv.w, 1);
      float right = __shfl_down(Bv.x, 1);
      float win[6];
      win[0] = left * mA;
      win[1] = Bv.x;
      win[2] = Bv.y;
      win[3] = Bv.z;
      win[4] = Bv.w;
      win[5] = right * mC;
      if (s4 < 3) {                        // ro=0, weight row s4
        const float* wk = &wch[3 * s4];
        const float* wv = &wch[9 + 3 * s4];
        #pragma unroll
        for (int cc = 0; cc < 4; ++cc) {
          float a = kacc[0][cc], b2 = vacc[0][cc];
          #pragma unroll
          for (int dxw = 0; dxw < 3; ++dxw) {
            float xv = win[cc + dxw];
            a  = fmaf(wk[dxw], xv, a);
            b2 = fmaf(wv[dxw], xv, b2);
          }
          kacc[0][cc] = a; vacc[0][cc] = b2;
        }
        if (roq == 0) {
          const float* wq = &wch[18 + 3 * s4];
          #pragma unroll
          for (int cc = 0; cc < 4; ++cc) {
            float qa = qacc[cc];
            #pragma unroll
            for (int dxw = 0; dxw < 3; ++dxw)
              qa = fmaf(wq[dxw], win[cc + dxw], qa);
            qacc[cc] = qa;
          }
        }
      }
      if (s4 >= 1) {                       // ro=1, weight row s4-1
        const float* wk = &wch[3 * (s4 - 1)];
        const float* wv = &wch[9 + 3 * (s4 - 1)];
        #pragma unroll
        for (int cc = 0; cc < 4; ++cc) {
          float a = kacc[1][cc], b2 = vacc[1][cc];
          #pragma unroll
          for (int dxw = 0; dxw < 3; ++dxw) {
            float xv = win[cc + dxw];
            a  = fmaf(wk[dxw], xv, a);
            b2 = fmaf(wv[dxw], xv, b2);
          }
          kacc[1][cc] = a; vacc[1][cc] = b2;
        }
        if (roq == 1) {
          const float* wq = &wch[18 + 3 * (s4 - 1)];
          #pragma unroll
          for (int cc = 0; cc < 4; ++cc) {
            float qa = qacc[cc];
            #pragma unroll
            for (int dxw = 0; dxw < 3; ++dxw)
              qa = fmaf(wq[dxw], win[cc + dxw], qa);
            qacc[cc] = qa;
          }
        }
      }
    }
    if (ci < 5) {
      #pragma unroll
      for (int s4 = 0; s4 < 4; ++s4) Bv4[s4] = Bn4[s4];
    }
  }

  // write K/V tiles (x1 col xc at slot xc+4, stride 272) + q + bias pad cols
  #pragma unroll
  for (int ro = 0; ro < 2; ++ro) {
    int r = 2 * rg + ro;
    *(float4*)&KT[r * 272 + 4 * cg + 4] =
        make_float4(kacc[ro][0], kacc[ro][1], kacc[ro][2], kacc[ro][3]);
    *(float4*)&VT[r * 272 + 4 * cg + 4] =
        make_float4(vacc[ro][0], vacc[ro][1], vacc[ro][2], vacc[ro][3]);
  }
  if (roq >= 0)
    *(float4*)&QS[(rg == 2 ? 256 : 0) + 4 * cg] =
        make_float4(qacc[0], qacc[1], qacc[2], qacc[3]);
  if (tid < 96) {                          // pad cols pc 0,1,2,259,260,261
    int t2 = tid;
    int kv = t2 >= 48; if (kv) t2 -= 48;
    int lr = t2 & 7, pi = t2 >> 3;
    int slot = (pi < 3) ? (pi + 1) : (pi + 257);
    (kv ? VT : KT)[lr * 272 + slot] = bsl[3 + kv];
  }
  __syncthreads();

  // ---- attention: 2 thr/pixel, one-pass softmax --------------------------
  {
    int half = tid & 1;
    int pix  = tid >> 1;
    int dx   = pix & 1;
    int ox   = (pix >> 1) & 31;
    int dy   = (pix >> 6) & 1;
    int wb   = 8 * ox + 4 * dx;
    int dv   = dx ? 0 : 3;
    int i0   = half * 3;

    float4 qv4 = *(const float4*)&QS[dy * 256 + wb];
    float qv0 = qv4.x, qv1 = qv4.y, qv2 = qv4.z, qv3 = qv4.w;
    float qsum = qv0 + qv1 + qv2 + qv3;

    float sum = 0.f, o = 0.f;
    #pragma unroll
    for (int ii = 0; ii < 4; ++ii) {
      int i = i0 + ii;
      float act = ((half == 0) || (ii > 0)) ? 1.0f : 0.0f;
      const float* kr = &KT[(dy + i) * 272 + wb];
      const float* vr = &VT[(dy + i) * 272 + wb];
      float B[12], BV[12];
      *(float4*)&B[0]  = *(const float4*)&kr[0];
      *(float4*)&B[4]  = *(const float4*)&kr[4];
      *(float4*)&B[8]  = *(const float4*)&kr[8];
      *(float4*)&BV[0] = *(const float4*)&vr[0];
      *(float4*)&BV[4] = *(const float4*)&vr[4];
      *(float4*)&BV[8] = *(const float4*)&vr[8];
      float rh = rhs[i];
      #pragma unroll
      for (int j = 0; j < 7; ++j) {
        float d0 = fmaf(qv0, B[j + 1],
                   fmaf(qv1, B[j + 2],
                   fmaf(qv2, B[j + 3], qv3 * B[j + 4])));
        float s = fmaf(qsum, rh + rws[j], d0);
        float e = act * __expf(s);
        sum += e;
        o = fmaf(e, BV[dv + j + 1], o);
      }
    }
    sum += __shfl_xor(sum, 1);
    o   += __shfl_xor(o, 1);

    float quarter = 0.25f * o / sum;
    float psum = quarter + __shfl_xor(quarter, 2);
    if ((tid & 3) == 0) red[dy * 32 + ox] = psum;
  }
  __syncthreads();

  if (tid < 32) {
    float scv = red[tid] + red[32 + tid];  // sc[c][oy][tid]
    float e0  = __shfl(scv, 0, 32);
    float e31 = __shfl(scv, 31, 32);
    float rs = scv;
    #pragma unroll
    for (int off = 16; off >= 1; off >>= 1) rs += __shfl_down(rs, off, 32);
    if (tid == 0) {
      float* pa = statA + (c * 32 + oy) * 3;
      pa[0] = rs; pa[1] = e0; pa[2] = e31;
    }
  }
}

// K2: out[o] = fcb'[o] + (G[o,:].S + Gb[o,:].Sx)/1024. 20 blocks x 64 lanes.
__global__ __launch_bounds__(64) void k_out(
    const float* __restrict__ statA, const float* __restrict__ Sx,
    const float* __restrict__ G, const float* __restrict__ Gb,
    const float* __restrict__ FCB2, float* __restrict__ out) {
  __shared__ float Sl[288];
  __shared__ float SxL[54];
  int o = blockIdx.x, lane = threadIdx.x;
  if (lane < 32) {
    int ch = lane;
    const float* pa = statA + ch * 96;
    float T = 0.f, C0 = 0.f, C31 = 0.f;
    #pragma unroll
    for (int i = 0; i < 32; ++i) {
      T += pa[3 * i]; C0 += pa[3 * i + 1]; C31 += pa[3 * i + 2];
    }
    float r0 = pa[0],  e00 = pa[1],    e0_31 = pa[2];
    float r31 = pa[93], e31_0 = pa[94], e31_31 = pa[95];
    #pragma unroll
    for (int ky = 0; ky < 3; ++ky) {
      float exR = (ky == 0) ? r31 : (ky == 2 ? r0 : 0.f);
      #pragma unroll
      for (int kx = 0; kx < 3; ++kx) {
        float exC = (kx == 0) ? C31 : (kx == 2 ? C0 : 0.f);
        float corner = 0.f;
        if (ky != 1 && kx != 1) {
          if (ky == 0) corner = (kx == 0) ? e31_31 : e31_0;
          else         corner = (kx == 0) ? e0_31  : e00;
        }
        Sl[ch * 9 + ky * 3 + kx] = T - exR - exC + corner;
      }
    }
  } else {
    for (int idx = lane - 32; idx < 54; idx += 32) SxL[idx] = Sx[idx];
  }
  __syncthreads();

  float acc = 0.f;
  #pragma unroll
  for (int i0 = 0; i0 < 288; i0 += 64) {
    int i = i0 + lane;
    if (i < 288) acc = fmaf(G[o * 288 + i], Sl[i], acc);
  }
  if (lane < 54) acc = fmaf(Gb[o * 54 + lane], SxL[lane], acc);
  #pragma unroll
  for (int off = 32; off >= 1; off >>= 1) acc += __shfl_down(acc, off);
  if (lane == 0) out[o] = FCB2[o] + acc * (1.0f / 1024.0f);
}

extern "C" void kernel_launch(void* const* d_in, const int* in_sizes, int n_in,
                              void* d_out, int out_size, void* d_ws, size_t ws_size,
                              hipStream_t stream) {
  const float* x    = (const float*)d_in[0];
  // d_in[1] = diff_input (int, always 1) -> attention branch always taken
  const float* bw   = (const float*)d_in[2];
  const float* bb   = (const float*)d_in[3];
  const float* c1w  = (const float*)d_in[4];
  const float* c1b  = (const float*)d_in[5];
  const float* kw   = (const float*)d_in[6];
  const float* kb   = (const float*)d_in[7];
  const float* qw   = (const float*)d_in[8];
  const float* qb   = (const float*)d_in[9];
  const float* vw   = (const float*)d_in[10];
  const float* vb   = (const float*)d_in[11];
  const float* relh = (const float*)d_in[12];
  const float* relw = (const float*)d_in[13];
  const float* ew   = (const float*)d_in[14];
  const float* eb   = (const float*)d_in[15];
  const float* fcw  = (const float*)d_in[16];
  const float* fcb  = (const float*)d_in[17];

  float* ws    = (float*)d_ws;
  float* statA = ws + OFF_STATA;
  float* Sxb   = ws + OFF_SX;
  float* Gm    = ws + OFF_G;
  float* Gbm   = ws + OFF_GB;
  float* FCB2  = ws + OFF_FCB2;
  float* out   = (float*)d_out;

  k_fused<<<1205, 256, 0, stream>>>(x, c1w, c1b, kw, kb, qw, qb, vw, vb,
                                    relh, relw, bw, bb, ew, eb, fcw, fcb,
                                    statA, Sxb, Gm, Gbm, FCB2);
  k_out  <<<20,   64,  0, stream>>>(statA, Sxb, Gm, Gbm, FCB2, out);
}